// Round 5
// baseline (1420.886 us; speedup 1.0000x reference)
//
#include <hip/hip_runtime.h>
#include <hip/hip_bf16.h>

using bf16 = __bf16;
typedef __attribute__((ext_vector_type(4))) __bf16 bf16x4;
typedef __attribute__((ext_vector_type(8))) __bf16 bf16x8;
typedef __attribute__((ext_vector_type(4))) float  f32x4;

static constexpr int D_    = 128;
static constexpr int TWOD_ = 256;

// ---------------- prep: pack/split weights ----------------
// W1c [1024][128] hi/lo bf16: rows 0-255 = W1[:, :128] (Pa), 256-511 = W1[:,128:] (Pb),
//                             512-767 = rW1[:, :128] (Pra), 768-1023 = rW1[:,128:] (Prb)
// W2c [256][512] hi/lo bf16: k<256 = W2, k>=256 = rW2
__global__ void k_prep(const float* __restrict__ W1, const float* __restrict__ W2,
                       const float* __restrict__ rW1, const float* __restrict__ rW2,
                       const float* __restrict__ W_ih, const float* __restrict__ W_hh,
                       bf16* __restrict__ W1chi, bf16* __restrict__ W1clo,
                       bf16* __restrict__ W2chi, bf16* __restrict__ W2clo,
                       float* __restrict__ W_ihT, float* __restrict__ W_hhT)
{
    int i = blockIdx.x * 256 + threadIdx.x;
    if (i < 1024 * 128) {
        int c = i >> 7, k = i & 127;
        float v;
        if      (c < 256) v = W1[c * 256 + k];
        else if (c < 512) v = W1[(c - 256) * 256 + 128 + k];
        else if (c < 768) v = rW1[(c - 512) * 256 + k];
        else              v = rW1[(c - 768) * 256 + 128 + k];
        bf16 hi = (bf16)v;
        W1chi[i] = hi;
        W1clo[i] = (bf16)(v - (float)hi);
    }
    if (i < 256 * 512) {
        int o = i >> 9, k = i & 511;
        float v = (k < 256) ? W2[o * 256 + k] : rW2[o * 256 + (k - 256)];
        bf16 hi = (bf16)v;
        W2chi[i] = hi;
        W2clo[i] = (bf16)(v - (float)hi);
    }
    if (i < 384 * 384) { int o = i / 384, k = i % 384; W_ihT[k * 384 + o] = W_ih[i]; }
    if (i < 384 * 128) { int o = i / 128, k = i % 128; W_hhT[k * 384 + o] = W_hh[i]; }
}

// ---------------- counting sort ----------------
__global__ void k_hist(const int* __restrict__ from_idx, const int* __restrict__ to_idx,
                       int* __restrict__ hist_to, int* __restrict__ hist_from, int E)
{
    int e = blockIdx.x * 256 + threadIdx.x;
    if (e < E) {
        atomicAdd(&hist_to[to_idx[e]], 1);
        atomicAdd(&hist_from[from_idx[e]], 1);
    }
}

__global__ void k_scan(const int* __restrict__ histA, int* __restrict__ ofsA,
                       const int* __restrict__ histB, int* __restrict__ ofsB, int n)
{
    const int* hist = blockIdx.x ? histB : histA;
    int* ofs        = blockIdx.x ? ofsB  : ofsA;
    __shared__ int buf[1024];
    __shared__ int carry_s;
    if (threadIdx.x == 0) carry_s = 0;
    __syncthreads();
    for (int base = 0; base < n; base += 1024) {
        int i = base + threadIdx.x;
        int v = (i < n) ? hist[i] : 0;
        buf[threadIdx.x] = v;
        __syncthreads();
        for (int off = 1; off < 1024; off <<= 1) {
            int t = (threadIdx.x >= off) ? buf[threadIdx.x - off] : 0;
            __syncthreads();
            buf[threadIdx.x] += t;
            __syncthreads();
        }
        int incl = buf[threadIdx.x];
        if (i < n) ofs[i] = carry_s + incl - v;   // exclusive
        __syncthreads();
        if (threadIdx.x == 1023) carry_s += buf[1023];
        __syncthreads();
    }
}

__global__ void k_scatter(const int* __restrict__ from_idx, const int* __restrict__ to_idx,
                          int* __restrict__ cur_to, int* __restrict__ cur_from,
                          int2* __restrict__ sorted_fwd, int2* __restrict__ sorted_rev, int E)
{
    int e = blockIdx.x * 256 + threadIdx.x;
    if (e < E) {
        int f = from_idx[e], t = to_idx[e];
        int p = atomicAdd(&cur_to[t], 1);
        sorted_fwd[p] = make_int2(f, t);      // (src, dst) for forward dir
        int q = atomicAdd(&cur_from[f], 1);
        sorted_rev[q] = make_int2(t, f);      // (src, dst) for reverse dir
    }
}

// ---------------- node-level layer-1 GEMM (exact: hi/lo x hi/lo, 3 passes) ----------------
// One direction per launch (W1hi/W1lo pre-offset). blockIdx.y: 0 -> Pa (bf16), 1 -> Pb (f32).
__global__ __launch_bounds__(256, 2) void k_nodeL1(
    const float* __restrict__ h, const bf16* __restrict__ W1hi, const bf16* __restrict__ W1lo,
    bf16* __restrict__ Pa, float* __restrict__ Pb, int N)
{
    __shared__ __align__(16) bf16 Ahh[128][136];
    __shared__ __align__(16) bf16 Ahl[128][136];
    const int tid = threadIdx.x;
    const int wave = tid >> 6, lane = tid & 63;
    const int l15 = lane & 15, lg = lane >> 4;
    const int rb = blockIdx.x * 128;
    const int table = blockIdx.y;                 // 0: a-table, 1: b-table

    #pragma unroll
    for (int it = 0; it < 16; ++it) {
        int idx = it * 256 + tid;
        int row = idx >> 5, col = (idx & 31) * 4;
        int grow = rb + row;
        float4 v = make_float4(0.f, 0.f, 0.f, 0.f);
        if (grow < N) v = *reinterpret_cast<const float4*>(&h[(size_t)grow * D_ + col]);
        bf16x4 bh, bl;
        bh[0] = (bf16)v.x; bl[0] = (bf16)(v.x - (float)bh[0]);
        bh[1] = (bf16)v.y; bl[1] = (bf16)(v.y - (float)bh[1]);
        bh[2] = (bf16)v.z; bl[2] = (bf16)(v.z - (float)bh[2]);
        bh[3] = (bf16)v.w; bl[3] = (bf16)(v.w - (float)bh[3]);
        *reinterpret_cast<bf16x4*>(&Ahh[row][col]) = bh;
        *reinterpret_cast<bf16x4*>(&Ahl[row][col]) = bl;
    }
    __syncthreads();

    f32x4 acc[8][4];
    #pragma unroll
    for (int rt = 0; rt < 8; ++rt)
        #pragma unroll
        for (int ct = 0; ct < 4; ++ct) acc[rt][ct] = f32x4{0.f, 0.f, 0.f, 0.f};

    #pragma unroll
    for (int kk = 0; kk < 4; ++kk) {
        int k0 = kk * 32 + lg * 8;
        bf16x8 ahi[8], alo[8];
        #pragma unroll
        for (int rt = 0; rt < 8; ++rt) {
            ahi[rt] = *reinterpret_cast<const bf16x8*>(&Ahh[rt * 16 + l15][k0]);
            alo[rt] = *reinterpret_cast<const bf16x8*>(&Ahl[rt * 16 + l15][k0]);
        }
        #pragma unroll
        for (int ct = 0; ct < 4; ++ct) {
            int c512 = table * 256 + wave * 64 + ct * 16 + l15;
            bf16x8 whi = *reinterpret_cast<const bf16x8*>(&W1hi[(size_t)c512 * 128 + k0]);
            bf16x8 wlo = *reinterpret_cast<const bf16x8*>(&W1lo[(size_t)c512 * 128 + k0]);
            #pragma unroll
            for (int rt = 0; rt < 8; ++rt) {
                acc[rt][ct] = __builtin_amdgcn_mfma_f32_16x16x32_bf16(ahi[rt], whi, acc[rt][ct], 0, 0, 0);
                acc[rt][ct] = __builtin_amdgcn_mfma_f32_16x16x32_bf16(ahi[rt], wlo, acc[rt][ct], 0, 0, 0);
                acc[rt][ct] = __builtin_amdgcn_mfma_f32_16x16x32_bf16(alo[rt], whi, acc[rt][ct], 0, 0, 0);
            }
        }
    }

    if (table) {
        #pragma unroll
        for (int ct = 0; ct < 4; ++ct) {
            int col = wave * 64 + ct * 16 + l15;
            #pragma unroll
            for (int rt = 0; rt < 8; ++rt)
                #pragma unroll
                for (int r = 0; r < 4; ++r) {
                    int node = rb + rt * 16 + lg * 4 + r;   // C/D: col=l15, row=lg*4+reg
                    if (node < N) Pb[(size_t)node * TWOD_ + col] = acc[rt][ct][r];
                }
        }
    } else {
        #pragma unroll
        for (int ct = 0; ct < 4; ++ct) {
            int col = wave * 64 + ct * 16 + l15;
            #pragma unroll
            for (int rt = 0; rt < 8; ++rt)
                #pragma unroll
                for (int r = 0; r < 4; ++r) {
                    int node = rb + rt * 16 + lg * 4 + r;
                    if (node < N) Pa[(size_t)node * TWOD_ + col] = (bf16)acc[rt][ct][r];
                }
        }
    }
}

// ---------------- edge pass: Y = relu(Pa[src]+Pb[dst]+b1), segment-accumulate into S ----------------
__global__ __launch_bounds__(256, 4) void k_edgeY(
    const int2* __restrict__ sorted, const bf16* __restrict__ Pa, const float* __restrict__ Pb,
    const float* __restrict__ b1v, float* __restrict__ S, int E)
{
    const int gw = (blockIdx.x * 256 + threadIdx.x) >> 6;   // global wave id
    const int lane = threadIdx.x & 63;
    int r0 = gw * 64;
    if (r0 >= E) return;
    int r1 = min(r0 + 64, E);
    const int c4 = lane * 4;
    float4 bias = *reinterpret_cast<const float4*>(&b1v[c4]);
    float a0 = 0.f, a1 = 0.f, a2 = 0.f, a3 = 0.f;
    float p0 = 0.f, p1 = 0.f, p2 = 0.f, p3 = 0.f;
    int cur = -1;
    for (int r = r0; r < r1; ++r) {
        int2 ed = sorted[r];                                // wave-uniform
        if (ed.y != cur) {
            if (cur >= 0) {
                float* s = &S[(size_t)cur * TWOD_ + c4];
                atomicAdd(s + 0, a0); atomicAdd(s + 1, a1);
                atomicAdd(s + 2, a2); atomicAdd(s + 3, a3);
            }
            a0 = a1 = a2 = a3 = 0.f;
            cur = ed.y;
            float4 pb = *reinterpret_cast<const float4*>(&Pb[(size_t)cur * TWOD_ + c4]);
            p0 = pb.x; p1 = pb.y; p2 = pb.z; p3 = pb.w;
        }
        bf16x4 pa = *reinterpret_cast<const bf16x4*>(&Pa[(size_t)ed.x * TWOD_ + c4]);
        a0 += fmaxf((float)pa[0] + p0 + bias.x, 0.f);
        a1 += fmaxf((float)pa[1] + p1 + bias.y, 0.f);
        a2 += fmaxf((float)pa[2] + p2 + bias.z, 0.f);
        a3 += fmaxf((float)pa[3] + p3 + bias.w, 0.f);
    }
    if (cur >= 0) {
        float* s = &S[(size_t)cur * TWOD_ + c4];
        atomicAdd(s + 0, a0); atomicAdd(s + 1, a1);
        atomicAdd(s + 2, a2); atomicAdd(s + 3, a3);
    }
}

// ---------------- node-level layer-2 GEMM (bf16x3 split): msgs = [Sf|Sr] @ W2cT ----------------
__global__ __launch_bounds__(256, 2) void k_nodeL2(
    const float* __restrict__ Sf, const float* __restrict__ Sr,
    const bf16* __restrict__ W2chi, const bf16* __restrict__ W2clo,
    float* __restrict__ msgs, int N)
{
    __shared__ __align__(16) bf16 Ah[128][72];
    __shared__ __align__(16) bf16 Al[128][72];
    const int tid = threadIdx.x;
    const int wave = tid >> 6, lane = tid & 63;
    const int l15 = lane & 15, lg = lane >> 4;
    const int rb = blockIdx.x * 128;

    f32x4 acc[8][4];
    #pragma unroll
    for (int rt = 0; rt < 8; ++rt)
        #pragma unroll
        for (int ct = 0; ct < 4; ++ct) acc[rt][ct] = f32x4{0.f, 0.f, 0.f, 0.f};

    for (int kc = 0; kc < 8; ++kc) {
        const float* Ssrc = (kc < 4) ? Sf : Sr;
        const int kb = (kc & 3) * 64;
        __syncthreads();                         // prior chunk's LDS reads done
        #pragma unroll
        for (int it = 0; it < 8; ++it) {
            int idx = it * 256 + tid;
            int row = idx >> 4, col = (idx & 15) * 4;
            int grow = rb + row;
            float4 v = make_float4(0.f, 0.f, 0.f, 0.f);
            if (grow < N) v = *reinterpret_cast<const float4*>(&Ssrc[(size_t)grow * TWOD_ + kb + col]);
            bf16x4 bh, bl;
            bh[0] = (bf16)v.x; bl[0] = (bf16)(v.x - (float)bh[0]);
            bh[1] = (bf16)v.y; bl[1] = (bf16)(v.y - (float)bh[1]);
            bh[2] = (bf16)v.z; bl[2] = (bf16)(v.z - (float)bh[2]);
            bh[3] = (bf16)v.w; bl[3] = (bf16)(v.w - (float)bh[3]);
            *reinterpret_cast<bf16x4*>(&Ah[row][col]) = bh;
            *reinterpret_cast<bf16x4*>(&Al[row][col]) = bl;
        }
        __syncthreads();

        #pragma unroll
        for (int ks = 0; ks < 2; ++ks) {
            int k0 = ks * 32 + lg * 8;
            int kglob = kc * 64 + k0;
            bf16x8 ahi[8], alo[8];
            #pragma unroll
            for (int rt = 0; rt < 8; ++rt) {
                ahi[rt] = *reinterpret_cast<const bf16x8*>(&Ah[rt * 16 + l15][k0]);
                alo[rt] = *reinterpret_cast<const bf16x8*>(&Al[rt * 16 + l15][k0]);
            }
            #pragma unroll
            for (int ct = 0; ct < 4; ++ct) {
                int c = wave * 64 + ct * 16 + l15;
                bf16x8 whi = *reinterpret_cast<const bf16x8*>(&W2chi[(size_t)c * 512 + kglob]);
                bf16x8 wlo = *reinterpret_cast<const bf16x8*>(&W2clo[(size_t)c * 512 + kglob]);
                #pragma unroll
                for (int rt = 0; rt < 8; ++rt) {
                    acc[rt][ct] = __builtin_amdgcn_mfma_f32_16x16x32_bf16(ahi[rt], whi, acc[rt][ct], 0, 0, 0);
                    acc[rt][ct] = __builtin_amdgcn_mfma_f32_16x16x32_bf16(ahi[rt], wlo, acc[rt][ct], 0, 0, 0);
                    acc[rt][ct] = __builtin_amdgcn_mfma_f32_16x16x32_bf16(alo[rt], whi, acc[rt][ct], 0, 0, 0);
                }
            }
        }
    }

    #pragma unroll
    for (int ct = 0; ct < 4; ++ct) {
        int col = wave * 64 + ct * 16 + l15;
        #pragma unroll
        for (int rt = 0; rt < 8; ++rt)
            #pragma unroll
            for (int r = 0; r < 4; ++r) {
                int node = rb + rt * 16 + lg * 4 + r;
                if (node < N) msgs[(size_t)node * TWOD_ + col] = acc[rt][ct][r];
            }
    }
}

// ---------------- GRU cell (f32 vector); deg-bias folded into staging ----------------
__global__ __launch_bounds__(256, 2) void k_gru(
    const float* __restrict__ msgs, const float* __restrict__ feat,
    const float* __restrict__ h,
    const float* __restrict__ W_ihT, const float* __restrict__ W_hhT,
    const float* __restrict__ b_ih, const float* __restrict__ b_hh,
    const float* __restrict__ b2v, const float* __restrict__ rb2v,
    const int* __restrict__ deg_to, const int* __restrict__ deg_from,
    float* __restrict__ out, int N)
{
    __shared__ float in_lds[32][384];   // [msgs+degbias (256) | feat (128)]
    __shared__ float h_lds[32][128];
    const int tid = threadIdx.x, wave = tid >> 6, lane = tid & 63;
    const int nb = blockIdx.x * 32;

    for (int idx = tid; idx < 32 * 64; idx += 256) {
        int r = idx >> 6, q4 = (idx & 63) * 4;
        int node = nb + r;
        float4 v = make_float4(0.f, 0.f, 0.f, 0.f);
        if (node < N) {
            float4 m  = *reinterpret_cast<const float4*>(&msgs[(size_t)node * 256 + q4]);
            float4 vb = *reinterpret_cast<const float4*>(&b2v[q4]);
            float4 vr = *reinterpret_cast<const float4*>(&rb2v[q4]);
            float dt = (float)deg_to[node], df = (float)deg_from[node];
            v.x = m.x + dt * vb.x + df * vr.x;
            v.y = m.y + dt * vb.y + df * vr.y;
            v.z = m.z + dt * vb.z + df * vr.z;
            v.w = m.w + dt * vb.w + df * vr.w;
        }
        *reinterpret_cast<float4*>(&in_lds[r][q4]) = v;
    }
    for (int idx = tid; idx < 32 * 32; idx += 256) {
        int r = idx >> 5, q = idx & 31;
        int node = nb + r;
        float4 v = make_float4(0.f, 0.f, 0.f, 0.f), w = v;
        if (node < N) {
            v = *reinterpret_cast<const float4*>(&feat[(size_t)node * 128 + q * 4]);
            w = *reinterpret_cast<const float4*>(&h[(size_t)node * 128 + q * 4]);
        }
        *reinterpret_cast<float4*>(&in_lds[r][256 + q * 4]) = v;
        *reinterpret_cast<float4*>(&h_lds[r][q * 4]) = w;
    }
    __syncthreads();

    float gi[8][6], gh[8][6];
    #pragma unroll
    for (int c = 0; c < 6; ++c) {
        float bi = b_ih[c * 64 + lane], bh = b_hh[c * 64 + lane];
        #pragma unroll
        for (int r = 0; r < 8; ++r) { gi[r][c] = bi; gh[r][c] = bh; }
    }
    #pragma unroll 2
    for (int k = 0; k < 384; ++k) {
        float w[6];
        #pragma unroll
        for (int c = 0; c < 6; ++c) w[c] = W_ihT[k * 384 + c * 64 + lane];
        #pragma unroll
        for (int r = 0; r < 8; ++r) {
            float x = in_lds[wave * 8 + r][k];
            #pragma unroll
            for (int c = 0; c < 6; ++c) gi[r][c] = fmaf(x, w[c], gi[r][c]);
        }
    }
    #pragma unroll 2
    for (int k = 0; k < 128; ++k) {
        float w[6];
        #pragma unroll
        for (int c = 0; c < 6; ++c) w[c] = W_hhT[k * 384 + c * 64 + lane];
        #pragma unroll
        for (int r = 0; r < 8; ++r) {
            float x = h_lds[wave * 8 + r][k];
            #pragma unroll
            for (int c = 0; c < 6; ++c) gh[r][c] = fmaf(x, w[c], gh[r][c]);
        }
    }
    #pragma unroll
    for (int r = 0; r < 8; ++r) {
        int node = nb + wave * 8 + r;
        if (node >= N) continue;
        #pragma unroll
        for (int c2 = 0; c2 < 2; ++c2) {
            int j = c2 * 64 + lane;
            float rr = 1.f / (1.f + __expf(-(gi[r][c2]     + gh[r][c2])));
            float zz = 1.f / (1.f + __expf(-(gi[r][c2 + 2] + gh[r][c2 + 2])));
            float nn = tanhf(gi[r][c2 + 4] + rr * gh[r][c2 + 4]);
            float hv = h_lds[wave * 8 + r][j];
            out[(size_t)node * 128 + j] = (1.f - zz) * nn + zz * hv;
        }
    }
}

extern "C" void kernel_launch(void* const* d_in, const int* in_sizes, int n_in,
                              void* d_out, int out_size, void* d_ws, size_t ws_size,
                              hipStream_t stream)
{
    const float* h    = (const float*)d_in[0];
    const float* feat = (const float*)d_in[1];
    const float* W1   = (const float*)d_in[2];
    const float* b1   = (const float*)d_in[3];
    const float* W2   = (const float*)d_in[4];
    const float* b2   = (const float*)d_in[5];
    const float* rW1  = (const float*)d_in[6];
    const float* rb1  = (const float*)d_in[7];
    const float* rW2  = (const float*)d_in[8];
    const float* rb2  = (const float*)d_in[9];
    const float* W_ih = (const float*)d_in[10];
    const float* W_hh = (const float*)d_in[11];
    const float* b_ih = (const float*)d_in[12];
    const float* b_hh = (const float*)d_in[13];
    const int* from_idx = (const int*)d_in[14];
    const int* to_idx   = (const int*)d_in[15];
    const int E = in_sizes[14];
    const int N = in_sizes[0] / D_;
    float* out = (float*)d_out;

    // ---- workspace layout (~195 MB peak; previous 271 MB overflowed d_ws) ----
    char* p = (char*)d_ws;
    auto take = [&](size_t bytes) { char* r = p; p += (bytes + 255) & ~(size_t)255; return r; };
    // P block: Pa bf16 [N,256] + Pb f32 [N,256]; reused for both directions.
    // msgs f32 [N,256] aliases this block (P dead after both edge passes).
    char*  Pblk      = take((size_t)N * TWOD_ * (sizeof(bf16) + sizeof(float)));   // 76.8 MB
    bf16*  Pa        = (bf16*)Pblk;
    float* Pb        = (float*)(Pblk + (size_t)N * TWOD_ * sizeof(bf16));
    float* msgs      = (float*)Pblk;
    float* S_fwd     = (float*)take((size_t)N * TWOD_ * sizeof(float));            // 51.2 MB
    float* S_rev     = (float*)take((size_t)N * TWOD_ * sizeof(float));            // 51.2 MB
    int2*  sorted_fwd = (int2*)take((size_t)E * sizeof(int2));                     // 6.4 MB
    int2*  sorted_rev = (int2*)take((size_t)E * sizeof(int2));                     // 6.4 MB
    bf16*  W1chi     = (bf16*) take(1024 * 128 * sizeof(bf16));
    bf16*  W1clo     = (bf16*) take(1024 * 128 * sizeof(bf16));
    bf16*  W2chi     = (bf16*) take(256 * 512 * sizeof(bf16));
    bf16*  W2clo     = (bf16*) take(256 * 512 * sizeof(bf16));
    float* W_ihT     = (float*)take(384 * 384 * sizeof(float));
    float* W_hhT     = (float*)take(128 * 384 * sizeof(float));
    int*   hist_to   = (int*)  take((size_t)N * sizeof(int));
    int*   hist_from = (int*)  take((size_t)N * sizeof(int));
    int*   ofs_to    = (int*)  take((size_t)N * sizeof(int));
    int*   ofs_from  = (int*)  take((size_t)N * sizeof(int));

    hipMemsetAsync(S_fwd, 0, (size_t)N * TWOD_ * sizeof(float), stream);
    hipMemsetAsync(S_rev, 0, (size_t)N * TWOD_ * sizeof(float), stream);
    hipMemsetAsync(hist_to, 0, (size_t)N * sizeof(int), stream);
    hipMemsetAsync(hist_from, 0, (size_t)N * sizeof(int), stream);

    k_prep<<<576, 256, 0, stream>>>(W1, W2, rW1, rW2, W_ih, W_hh,
                                    W1chi, W1clo, W2chi, W2clo, W_ihT, W_hhT);
    int gE = (E + 255) / 256;
    k_hist<<<gE, 256, 0, stream>>>(from_idx, to_idx, hist_to, hist_from, E);
    k_scan<<<2, 1024, 0, stream>>>(hist_to, ofs_to, hist_from, ofs_from, N);
    k_scatter<<<gE, 256, 0, stream>>>(from_idx, to_idx, ofs_to, ofs_from,
                                      sorted_fwd, sorted_rev, E);

    dim3 g1((N + 127) / 128, 2);
    int gEdge = (E + 64 * 4 - 1) / (64 * 4);     // 64 rows/wave, 4 waves/block

    // forward direction: tables from W1 (rows 0..511 of packed W1c)
    k_nodeL1<<<g1, 256, 0, stream>>>(h, W1chi, W1clo, Pa, Pb, N);
    k_edgeY<<<gEdge, 256, 0, stream>>>(sorted_fwd, Pa, Pb, b1, S_fwd, E);

    // reverse direction: tables from rW1 (rows 512..1023), reusing Pa/Pb
    k_nodeL1<<<g1, 256, 0, stream>>>(h, W1chi + 512 * 128, W1clo + 512 * 128, Pa, Pb, N);
    k_edgeY<<<gEdge, 256, 0, stream>>>(sorted_rev, Pa, Pb, rb1, S_rev, E);

    k_nodeL2<<<(N + 127) / 128, 256, 0, stream>>>(S_fwd, S_rev, W2chi, W2clo, msgs, N);

    k_gru<<<(N + 31) / 32, 256, 0, stream>>>(msgs, feat, h, W_ihT, W_hhT, b_ih, b_hh,
                                             b2, rb2, hist_to, hist_from, out, N);
}

// Round 6
// 1138.390 us; speedup vs baseline: 1.2482x; 1.2482x over previous
//
#include <hip/hip_runtime.h>
#include <hip/hip_bf16.h>

using bf16 = __bf16;
typedef __attribute__((ext_vector_type(4))) __bf16 bf16x4;
typedef __attribute__((ext_vector_type(8))) __bf16 bf16x8;
typedef __attribute__((ext_vector_type(4))) float  f32x4;

static constexpr int D_    = 128;
static constexpr int TWOD_ = 256;

// ---------------- prep: split W1 into hi/lo bf16 ----------------
// W1c [1024][128]: rows 0-255 = W1[:, :128] (Pa), 256-511 = W1[:,128:] (Pb),
//                  512-767 = rW1[:, :128] (Pra), 768-1023 = rW1[:,128:] (Prb)
__global__ void k_prep(const float* __restrict__ W1, const float* __restrict__ rW1,
                       bf16* __restrict__ W1chi, bf16* __restrict__ W1clo)
{
    int i = blockIdx.x * 256 + threadIdx.x;
    if (i < 1024 * 128) {
        int c = i >> 7, k = i & 127;
        float v;
        if      (c < 256) v = W1[c * 256 + k];
        else if (c < 512) v = W1[(c - 256) * 256 + 128 + k];
        else if (c < 768) v = rW1[(c - 512) * 256 + k];
        else              v = rW1[(c - 768) * 256 + 128 + k];
        bf16 hi = (bf16)v;
        W1chi[i] = hi;
        W1clo[i] = (bf16)(v - (float)hi);
    }
}

// ---------------- fold: Wgi = [W_ihA@W2 | W_ihA@rW2 | W_ihB] (384x640) hi/lo,
//                  Wgh = W_hh (384x128) hi/lo, cf = W_ihA@b2, cr = W_ihA@rb2 ----------------
__global__ void k_fold(const float* __restrict__ W_ih, const float* __restrict__ W_hh,
                       const float* __restrict__ W2, const float* __restrict__ rW2,
                       const float* __restrict__ b2, const float* __restrict__ rb2,
                       bf16* __restrict__ WgiHi, bf16* __restrict__ WgiLo,
                       bf16* __restrict__ WghHi, bf16* __restrict__ WghLo,
                       float* __restrict__ cf, float* __restrict__ cr)
{
    int idx = blockIdx.x * 256 + threadIdx.x;
    if (idx < 384 * 640) {
        int o = idx / 640, c = idx - o * 640;
        float v;
        if (c < 512) {
            const float* Wm = (c < 256) ? W2 : rW2;
            int cc = c & 255;
            float s = 0.f;
            for (int m = 0; m < 256; ++m)
                s = fmaf(W_ih[o * 384 + m], Wm[m * 256 + cc], s);
            v = s;
        } else {
            v = W_ih[o * 384 + 256 + (c - 512)];
        }
        bf16 hi = (bf16)v;
        WgiHi[idx] = hi;
        WgiLo[idx] = (bf16)(v - (float)hi);
    }
    if (idx < 384 * 128) {
        float v = W_hh[idx];
        bf16 hi = (bf16)v;
        WghHi[idx] = hi;
        WghLo[idx] = (bf16)(v - (float)hi);
    }
    if (idx < 384) {
        float sf = 0.f, sr = 0.f;
        for (int m = 0; m < 256; ++m) {
            float w = W_ih[idx * 384 + m];
            sf = fmaf(w, b2[m], sf);
            sr = fmaf(w, rb2[m], sr);
        }
        cf[idx] = sf;
        cr[idx] = sr;
    }
}

// ---------------- counting sort ----------------
__global__ void k_hist(const int* __restrict__ from_idx, const int* __restrict__ to_idx,
                       int* __restrict__ hist_to, int* __restrict__ hist_from, int E)
{
    int e = blockIdx.x * 256 + threadIdx.x;
    if (e < E) {
        atomicAdd(&hist_to[to_idx[e]], 1);
        atomicAdd(&hist_from[from_idx[e]], 1);
    }
}

// parallel scan, 3 phases. y: 0 -> A(to), 1 -> B(from)
__global__ void k_scanP(const int* __restrict__ histA, const int* __restrict__ histB,
                        int* __restrict__ ofsA, int* __restrict__ ofsB,
                        int* __restrict__ sumsA, int* __restrict__ sumsB, int n)
{
    const int* hist = blockIdx.y ? histB : histA;
    int* ofs        = blockIdx.y ? ofsB  : ofsA;
    int* sums       = blockIdx.y ? sumsB : sumsA;
    __shared__ int buf[1024];
    int i = blockIdx.x * 1024 + threadIdx.x;
    int v = (i < n) ? hist[i] : 0;
    buf[threadIdx.x] = v;
    __syncthreads();
    for (int off = 1; off < 1024; off <<= 1) {
        int t = (threadIdx.x >= off) ? buf[threadIdx.x - off] : 0;
        __syncthreads();
        buf[threadIdx.x] += t;
        __syncthreads();
    }
    if (i < n) ofs[i] = buf[threadIdx.x] - v;         // tile-local exclusive
    if (threadIdx.x == 1023) sums[blockIdx.x] = buf[1023];
}

__global__ void k_scanS(int* __restrict__ sumsA, int* __restrict__ sumsB, int nb)
{
    int* sums = blockIdx.x ? sumsB : sumsA;
    int lane = threadIdx.x;                            // 64 threads, nb <= 64
    int v = (lane < nb) ? sums[lane] : 0;
    int orig = v;
    for (int off = 1; off < 64; off <<= 1) {
        int t = __shfl_up(v, off, 64);
        if (lane >= off) v += t;
    }
    if (lane < nb) sums[lane] = v - orig;              // exclusive
}

__global__ void k_scanF(const int* __restrict__ sumsA, const int* __restrict__ sumsB,
                        int* __restrict__ ofsA, int* __restrict__ ofsB, int n)
{
    const int* sums = blockIdx.y ? sumsB : sumsA;
    int* ofs        = blockIdx.y ? ofsB  : ofsA;
    int i = blockIdx.x * 1024 + threadIdx.x;
    if (i < n) ofs[i] += sums[blockIdx.x];
}

__global__ void k_scatter(const int* __restrict__ from_idx, const int* __restrict__ to_idx,
                          int* __restrict__ cur_to, int* __restrict__ cur_from,
                          int2* __restrict__ sorted_fwd, int2* __restrict__ sorted_rev, int E)
{
    int e = blockIdx.x * 256 + threadIdx.x;
    if (e < E) {
        int f = from_idx[e], t = to_idx[e];
        int p = atomicAdd(&cur_to[t], 1);
        sorted_fwd[p] = make_int2(f, t);      // (src, dst) for forward dir
        int q = atomicAdd(&cur_from[f], 1);
        sorted_rev[q] = make_int2(t, f);      // (src, dst) for reverse dir
    }
}

// ---------------- node-level layer-1 GEMM (exact: hi/lo x hi/lo, 3 passes) ----------------
// One direction per launch (W1hi/W1lo pre-offset). blockIdx.y: 0 -> Pa (bf16), 1 -> Pb (f32).
__global__ __launch_bounds__(256, 2) void k_nodeL1(
    const float* __restrict__ h, const bf16* __restrict__ W1hi, const bf16* __restrict__ W1lo,
    bf16* __restrict__ Pa, float* __restrict__ Pb, int N)
{
    __shared__ __align__(16) bf16 Ahh[128][136];
    __shared__ __align__(16) bf16 Ahl[128][136];
    const int tid = threadIdx.x;
    const int wave = tid >> 6, lane = tid & 63;
    const int l15 = lane & 15, lg = lane >> 4;
    const int rb = blockIdx.x * 128;
    const int table = blockIdx.y;                 // 0: a-table, 1: b-table

    #pragma unroll
    for (int it = 0; it < 16; ++it) {
        int idx = it * 256 + tid;
        int row = idx >> 5, col = (idx & 31) * 4;
        int grow = rb + row;
        float4 v = make_float4(0.f, 0.f, 0.f, 0.f);
        if (grow < N) v = *reinterpret_cast<const float4*>(&h[(size_t)grow * D_ + col]);
        bf16x4 bh, bl;
        bh[0] = (bf16)v.x; bl[0] = (bf16)(v.x - (float)bh[0]);
        bh[1] = (bf16)v.y; bl[1] = (bf16)(v.y - (float)bh[1]);
        bh[2] = (bf16)v.z; bl[2] = (bf16)(v.z - (float)bh[2]);
        bh[3] = (bf16)v.w; bl[3] = (bf16)(v.w - (float)bh[3]);
        *reinterpret_cast<bf16x4*>(&Ahh[row][col]) = bh;
        *reinterpret_cast<bf16x4*>(&Ahl[row][col]) = bl;
    }
    __syncthreads();

    f32x4 acc[8][4];
    #pragma unroll
    for (int rt = 0; rt < 8; ++rt)
        #pragma unroll
        for (int ct = 0; ct < 4; ++ct) acc[rt][ct] = f32x4{0.f, 0.f, 0.f, 0.f};

    #pragma unroll
    for (int kk = 0; kk < 4; ++kk) {
        int k0 = kk * 32 + lg * 8;
        bf16x8 ahi[8], alo[8];
        #pragma unroll
        for (int rt = 0; rt < 8; ++rt) {
            ahi[rt] = *reinterpret_cast<const bf16x8*>(&Ahh[rt * 16 + l15][k0]);
            alo[rt] = *reinterpret_cast<const bf16x8*>(&Ahl[rt * 16 + l15][k0]);
        }
        #pragma unroll
        for (int ct = 0; ct < 4; ++ct) {
            int c512 = table * 256 + wave * 64 + ct * 16 + l15;
            bf16x8 whi = *reinterpret_cast<const bf16x8*>(&W1hi[(size_t)c512 * 128 + k0]);
            bf16x8 wlo = *reinterpret_cast<const bf16x8*>(&W1lo[(size_t)c512 * 128 + k0]);
            #pragma unroll
            for (int rt = 0; rt < 8; ++rt) {
                acc[rt][ct] = __builtin_amdgcn_mfma_f32_16x16x32_bf16(ahi[rt], whi, acc[rt][ct], 0, 0, 0);
                acc[rt][ct] = __builtin_amdgcn_mfma_f32_16x16x32_bf16(ahi[rt], wlo, acc[rt][ct], 0, 0, 0);
                acc[rt][ct] = __builtin_amdgcn_mfma_f32_16x16x32_bf16(alo[rt], whi, acc[rt][ct], 0, 0, 0);
            }
        }
    }

    if (table) {
        #pragma unroll
        for (int ct = 0; ct < 4; ++ct) {
            int col = wave * 64 + ct * 16 + l15;
            #pragma unroll
            for (int rt = 0; rt < 8; ++rt)
                #pragma unroll
                for (int r = 0; r < 4; ++r) {
                    int node = rb + rt * 16 + lg * 4 + r;   // C/D: col=l15, row=lg*4+reg
                    if (node < N) Pb[(size_t)node * TWOD_ + col] = acc[rt][ct][r];
                }
        }
    } else {
        #pragma unroll
        for (int ct = 0; ct < 4; ++ct) {
            int col = wave * 64 + ct * 16 + l15;
            #pragma unroll
            for (int rt = 0; rt < 8; ++rt)
                #pragma unroll
                for (int r = 0; r < 4; ++r) {
                    int node = rb + rt * 16 + lg * 4 + r;
                    if (node < N) Pa[(size_t)node * TWOD_ + col] = (bf16)acc[rt][ct][r];
                }
        }
    }
}

// ---------------- edge pass: Y = relu(Pa[src]+Pb[dst]+b1), segment-accumulate into S ----------------
__global__ __launch_bounds__(256, 4) void k_edgeY(
    const int2* __restrict__ sorted, const bf16* __restrict__ Pa, const float* __restrict__ Pb,
    const float* __restrict__ b1v, float* __restrict__ S, int E)
{
    const int gw = (blockIdx.x * 256 + threadIdx.x) >> 6;   // global wave id
    const int lane = threadIdx.x & 63;
    int r0 = gw * 64;
    if (r0 >= E) return;
    int r1 = min(r0 + 64, E);
    const int c4 = lane * 4;
    float4 bias = *reinterpret_cast<const float4*>(&b1v[c4]);
    float a0 = 0.f, a1 = 0.f, a2 = 0.f, a3 = 0.f;
    float p0 = 0.f, p1 = 0.f, p2 = 0.f, p3 = 0.f;
    int cur = -1;
    for (int r = r0; r < r1; ++r) {
        int2 ed = sorted[r];                                // wave-uniform
        if (ed.y != cur) {
            if (cur >= 0) {
                float* s = &S[(size_t)cur * TWOD_ + c4];
                atomicAdd(s + 0, a0); atomicAdd(s + 1, a1);
                atomicAdd(s + 2, a2); atomicAdd(s + 3, a3);
            }
            a0 = a1 = a2 = a3 = 0.f;
            cur = ed.y;
            float4 pb = *reinterpret_cast<const float4*>(&Pb[(size_t)cur * TWOD_ + c4]);
            p0 = pb.x; p1 = pb.y; p2 = pb.z; p3 = pb.w;
        }
        bf16x4 pa = *reinterpret_cast<const bf16x4*>(&Pa[(size_t)ed.x * TWOD_ + c4]);
        a0 += fmaxf((float)pa[0] + p0 + bias.x, 0.f);
        a1 += fmaxf((float)pa[1] + p1 + bias.y, 0.f);
        a2 += fmaxf((float)pa[2] + p2 + bias.z, 0.f);
        a3 += fmaxf((float)pa[3] + p3 + bias.w, 0.f);
    }
    if (cur >= 0) {
        float* s = &S[(size_t)cur * TWOD_ + c4];
        atomicAdd(s + 0, a0); atomicAdd(s + 1, a1);
        atomicAdd(s + 2, a2); atomicAdd(s + 3, a3);
    }
}

// ---------------- fused GRU-input GEMM (bf16x3 MFMA) ----------------
// y=0 (gi): out[N][384] = [Sf|Sr|feat] (K=640) @ Wgi^T    (10 K-chunks)
// y=1 (gh): out[N][384] = h (K=128) @ Wgh^T               (2 K-chunks)
// launched separately so gh can overwrite the S region after gi consumed it.
__global__ __launch_bounds__(384, 2) void k_gemm384(
    const float* __restrict__ Sf, const float* __restrict__ Sr,
    const float* __restrict__ feat, const float* __restrict__ h,
    const bf16* __restrict__ WHi, const bf16* __restrict__ WLo,
    float* __restrict__ Og, int nch, int wK, int N)
{
    __shared__ __align__(16) bf16 Ah[128][72];
    __shared__ __align__(16) bf16 Al[128][72];
    const int tid = threadIdx.x;
    const int wave = tid >> 6, lane = tid & 63;
    const int l15 = lane & 15, lg = lane >> 4;
    const int rb = blockIdx.x * 128;
    const bool is_gh = (wK == 128);

    f32x4 acc[8][4];
    #pragma unroll
    for (int rt = 0; rt < 8; ++rt)
        #pragma unroll
        for (int ct = 0; ct < 4; ++ct) acc[rt][ct] = f32x4{0.f, 0.f, 0.f, 0.f};

    for (int ch = 0; ch < nch; ++ch) {
        const float* X; int xstride, xoff;
        if (is_gh)       { X = h;    xstride = 128; xoff = ch * 64; }
        else if (ch < 4) { X = Sf;   xstride = 256; xoff = ch * 64; }
        else if (ch < 8) { X = Sr;   xstride = 256; xoff = (ch - 4) * 64; }
        else             { X = feat; xstride = 128; xoff = (ch - 8) * 64; }
        __syncthreads();
        for (int it = tid; it < 2048; it += 384) {      // 128 rows x 16 float4
            int row = it >> 4, col = (it & 15) * 4;
            int grow = rb + row;
            float4 v = make_float4(0.f, 0.f, 0.f, 0.f);
            if (grow < N) v = *reinterpret_cast<const float4*>(&X[(size_t)grow * xstride + xoff + col]);
            bf16x4 bh, bl;
            bh[0] = (bf16)v.x; bl[0] = (bf16)(v.x - (float)bh[0]);
            bh[1] = (bf16)v.y; bl[1] = (bf16)(v.y - (float)bh[1]);
            bh[2] = (bf16)v.z; bl[2] = (bf16)(v.z - (float)bh[2]);
            bh[3] = (bf16)v.w; bl[3] = (bf16)(v.w - (float)bh[3]);
            *reinterpret_cast<bf16x4*>(&Ah[row][col]) = bh;
            *reinterpret_cast<bf16x4*>(&Al[row][col]) = bl;
        }
        __syncthreads();

        #pragma unroll
        for (int ks = 0; ks < 2; ++ks) {
            int k0 = ks * 32 + lg * 8;
            int kglob = ch * 64 + k0;
            bf16x8 ahi[8], alo[8];
            #pragma unroll
            for (int rt = 0; rt < 8; ++rt) {
                ahi[rt] = *reinterpret_cast<const bf16x8*>(&Ah[rt * 16 + l15][k0]);
                alo[rt] = *reinterpret_cast<const bf16x8*>(&Al[rt * 16 + l15][k0]);
            }
            #pragma unroll
            for (int ct = 0; ct < 4; ++ct) {
                int c = wave * 64 + ct * 16 + l15;        // 6 waves x 64 = 384 cols
                bf16x8 whi = *reinterpret_cast<const bf16x8*>(&WHi[(size_t)c * wK + kglob]);
                bf16x8 wlo = *reinterpret_cast<const bf16x8*>(&WLo[(size_t)c * wK + kglob]);
                #pragma unroll
                for (int rt = 0; rt < 8; ++rt) {
                    acc[rt][ct] = __builtin_amdgcn_mfma_f32_16x16x32_bf16(ahi[rt], whi, acc[rt][ct], 0, 0, 0);
                    acc[rt][ct] = __builtin_amdgcn_mfma_f32_16x16x32_bf16(ahi[rt], wlo, acc[rt][ct], 0, 0, 0);
                    acc[rt][ct] = __builtin_amdgcn_mfma_f32_16x16x32_bf16(alo[rt], whi, acc[rt][ct], 0, 0, 0);
                }
            }
        }
    }

    #pragma unroll
    for (int ct = 0; ct < 4; ++ct) {
        int col = wave * 64 + ct * 16 + l15;
        #pragma unroll
        for (int rt = 0; rt < 8; ++rt)
            #pragma unroll
            for (int r = 0; r < 4; ++r) {
                int node = rb + rt * 16 + lg * 4 + r;     // C/D: col=l15, row=lg*4+reg
                if (node < N) Og[(size_t)node * 384 + col] = acc[rt][ct][r];
            }
    }
}

// ---------------- gate kernel: elementwise GRU gates ----------------
__global__ void k_gate(const float* __restrict__ giG, const float* __restrict__ ghG,
                       const float* __restrict__ h,
                       const float* __restrict__ b_ih, const float* __restrict__ b_hh,
                       const float* __restrict__ cf, const float* __restrict__ cr,
                       const int* __restrict__ deg_to, const int* __restrict__ deg_from,
                       float* __restrict__ out, int N)
{
    int idx = blockIdx.x * 256 + threadIdx.x;
    if (idx >= N * D_) return;
    int node = idx >> 7, j = idx & 127;
    float dt = (float)deg_to[node], df = (float)deg_from[node];
    size_t base = (size_t)node * 384;
    float gir = giG[base + j]       + b_ih[j]       + dt * cf[j]       + df * cr[j];
    float giz = giG[base + 128 + j] + b_ih[128 + j] + dt * cf[128 + j] + df * cr[128 + j];
    float gin = giG[base + 256 + j] + b_ih[256 + j] + dt * cf[256 + j] + df * cr[256 + j];
    float ghr = ghG[base + j]       + b_hh[j];
    float ghz = ghG[base + 128 + j] + b_hh[128 + j];
    float ghn = ghG[base + 256 + j] + b_hh[256 + j];
    float rr = 1.f / (1.f + __expf(-(gir + ghr)));
    float zz = 1.f / (1.f + __expf(-(giz + ghz)));
    float nn = tanhf(gin + rr * ghn);
    out[idx] = (1.f - zz) * nn + zz * h[idx];
}

extern "C" void kernel_launch(void* const* d_in, const int* in_sizes, int n_in,
                              void* d_out, int out_size, void* d_ws, size_t ws_size,
                              hipStream_t stream)
{
    const float* h    = (const float*)d_in[0];
    const float* feat = (const float*)d_in[1];
    const float* W1   = (const float*)d_in[2];
    const float* b1   = (const float*)d_in[3];
    const float* W2   = (const float*)d_in[4];
    const float* b2   = (const float*)d_in[5];
    const float* rW1  = (const float*)d_in[6];
    const float* rb1  = (const float*)d_in[7];
    const float* rW2  = (const float*)d_in[8];
    const float* rb2  = (const float*)d_in[9];
    const float* W_ih = (const float*)d_in[10];
    const float* W_hh = (const float*)d_in[11];
    const float* b_ih = (const float*)d_in[12];
    const float* b_hh = (const float*)d_in[13];
    const int* from_idx = (const int*)d_in[14];
    const int* to_idx   = (const int*)d_in[15];
    const int E = in_sizes[14];
    const int N = in_sizes[0] / D_;
    float* out = (float*)d_out;

    // ---- workspace (~196 MB peak; known-good scale) ----
    char* p = (char*)d_ws;
    auto take = [&](size_t bytes) { char* r = p; p += (bytes + 255) & ~(size_t)255; return r; };
    // P block (76.8 MB): Pa bf16 [N,256] + Pb f32 [N,256] during edge phase;
    // reused as giG f32 [N,384] afterwards (sizes match exactly).
    char*  Pblk      = take((size_t)N * TWOD_ * (sizeof(bf16) + sizeof(float)));
    bf16*  Pa        = (bf16*)Pblk;
    float* Pb        = (float*)(Pblk + (size_t)N * TWOD_ * sizeof(bf16));
    float* giG       = (float*)Pblk;
    // S block (102.4 MB): S_fwd + S_rev f32 [N,256]; reused as ghG f32 [N,384] (76.8 MB)
    char*  Sblk      = take((size_t)2 * N * TWOD_ * sizeof(float));
    float* S_fwd     = (float*)Sblk;
    float* S_rev     = (float*)(Sblk + (size_t)N * TWOD_ * sizeof(float));
    float* ghG       = (float*)Sblk;
    int2*  sorted_fwd = (int2*)take((size_t)E * sizeof(int2));
    int2*  sorted_rev = (int2*)take((size_t)E * sizeof(int2));
    bf16*  W1chi     = (bf16*) take(1024 * 128 * sizeof(bf16));
    bf16*  W1clo     = (bf16*) take(1024 * 128 * sizeof(bf16));
    bf16*  WgiHi     = (bf16*) take(384 * 640 * sizeof(bf16));
    bf16*  WgiLo     = (bf16*) take(384 * 640 * sizeof(bf16));
    bf16*  WghHi     = (bf16*) take(384 * 128 * sizeof(bf16));
    bf16*  WghLo     = (bf16*) take(384 * 128 * sizeof(bf16));
    float* cf        = (float*)take(384 * sizeof(float));
    float* cr        = (float*)take(384 * sizeof(float));
    int*   hist_to   = (int*)  take((size_t)N * sizeof(int));
    int*   hist_from = (int*)  take((size_t)N * sizeof(int));
    int*   ofs_to    = (int*)  take((size_t)N * sizeof(int));
    int*   ofs_from  = (int*)  take((size_t)N * sizeof(int));
    int*   sumsA     = (int*)  take(64 * sizeof(int));
    int*   sumsB     = (int*)  take(64 * sizeof(int));

    hipMemsetAsync(S_fwd, 0, (size_t)N * TWOD_ * sizeof(float), stream);
    hipMemsetAsync(S_rev, 0, (size_t)N * TWOD_ * sizeof(float), stream);
    hipMemsetAsync(hist_to, 0, (size_t)N * sizeof(int), stream);
    hipMemsetAsync(hist_from, 0, (size_t)N * sizeof(int), stream);

    k_prep<<<512, 256, 0, stream>>>(W1, rW1, W1chi, W1clo);
    k_fold<<<960, 256, 0, stream>>>(W_ih, W_hh, W2, rW2, b2, rb2,
                                    WgiHi, WgiLo, WghHi, WghLo, cf, cr);

    int gE = (E + 255) / 256;
    k_hist<<<gE, 256, 0, stream>>>(from_idx, to_idx, hist_to, hist_from, E);
    int nb = (N + 1023) / 1024;                       // 49 <= 64
    k_scanP<<<dim3(nb, 2), 1024, 0, stream>>>(hist_to, hist_from, ofs_to, ofs_from,
                                              sumsA, sumsB, N);
    k_scanS<<<2, 64, 0, stream>>>(sumsA, sumsB, nb);
    k_scanF<<<dim3(nb, 2), 1024, 0, stream>>>(sumsA, sumsB, ofs_to, ofs_from, N);
    k_scatter<<<gE, 256, 0, stream>>>(from_idx, to_idx, ofs_to, ofs_from,
                                      sorted_fwd, sorted_rev, E);

    dim3 g1((N + 127) / 128, 2);
    int gEdge = (E + 64 * 4 - 1) / (64 * 4);

    // forward direction (W1 rows 0..511 of packed table)
    k_nodeL1<<<g1, 256, 0, stream>>>(h, W1chi, W1clo, Pa, Pb, N);
    k_edgeY<<<gEdge, 256, 0, stream>>>(sorted_fwd, Pa, Pb, b1, S_fwd, E);
    // reverse direction (rW1 rows 512..1023), reusing Pa/Pb
    k_nodeL1<<<g1, 256, 0, stream>>>(h, W1chi + 512 * 128, W1clo + 512 * 128, Pa, Pb, N);
    k_edgeY<<<gEdge, 256, 0, stream>>>(sorted_rev, Pa, Pb, rb1, S_rev, E);

    int gN = (N + 127) / 128;
    // gi: consumes Sf/Sr/feat, writes giG (over dead P block)
    k_gemm384<<<gN, 384, 0, stream>>>(S_fwd, S_rev, feat, h, WgiHi, WgiLo, giG, 10, 640, N);
    // gh: reads only h, writes ghG (over dead S block) — ordered after gi by stream
    k_gemm384<<<gN, 384, 0, stream>>>(S_fwd, S_rev, feat, h, WghHi, WghLo, ghG, 2, 128, N);

    k_gate<<<(N * D_ + 255) / 256, 256, 0, stream>>>(giG, ghG, h, b_ih, b_hh, cf, cr,
                                                     hist_to, hist_from, out, N);
}

// Round 8
// 791.955 us; speedup vs baseline: 1.7941x; 1.4374x over previous
//
#include <hip/hip_runtime.h>
#include <hip/hip_bf16.h>

using bf16 = __bf16;
typedef __attribute__((ext_vector_type(4))) __bf16 bf16x4;
typedef __attribute__((ext_vector_type(8))) __bf16 bf16x8;
typedef __attribute__((ext_vector_type(4))) float  f32x4;

static constexpr int D_    = 128;
static constexpr int TWOD_ = 256;

// ---------------- prep: split W1 into hi/lo bf16 ----------------
// W1c [1024][128]: rows 0-255 = W1[:, :128] (Pa), 256-511 = W1[:,128:] (Pb),
//                  512-767 = rW1[:, :128] (Pra), 768-1023 = rW1[:,128:] (Prb)
__global__ void k_prep(const float* __restrict__ W1, const float* __restrict__ rW1,
                       bf16* __restrict__ W1chi, bf16* __restrict__ W1clo)
{
    int i = blockIdx.x * 256 + threadIdx.x;
    if (i < 1024 * 128) {
        int c = i >> 7, k = i & 127;
        float v;
        if      (c < 256) v = W1[c * 256 + k];
        else if (c < 512) v = W1[(c - 256) * 256 + 128 + k];
        else if (c < 768) v = rW1[(c - 512) * 256 + k];
        else              v = rW1[(c - 768) * 256 + 128 + k];
        bf16 hi = (bf16)v;
        W1chi[i] = hi;
        W1clo[i] = (bf16)(v - (float)hi);
    }
}

// ---------------- fold: Wgi = [W_ihA@W2 | W_ihA@rW2 | W_ihB] (384x640) hi/lo,
//                  Wgh = W_hh (384x128) hi/lo, cf = W_ihA@b2, cr = W_ihA@rb2 ----------------
__global__ void k_fold(const float* __restrict__ W_ih, const float* __restrict__ W_hh,
                       const float* __restrict__ W2, const float* __restrict__ rW2,
                       const float* __restrict__ b2, const float* __restrict__ rb2,
                       bf16* __restrict__ WgiHi, bf16* __restrict__ WgiLo,
                       bf16* __restrict__ WghHi, bf16* __restrict__ WghLo,
                       float* __restrict__ cf, float* __restrict__ cr)
{
    int idx = blockIdx.x * 256 + threadIdx.x;
    if (idx < 384 * 640) {
        int o = idx / 640, c = idx - o * 640;
        float v;
        if (c < 512) {
            const float* Wm = (c < 256) ? W2 : rW2;
            int cc = c & 255;
            float s = 0.f;
            for (int m = 0; m < 256; ++m)
                s = fmaf(W_ih[o * 384 + m], Wm[m * 256 + cc], s);
            v = s;
        } else {
            v = W_ih[o * 384 + 256 + (c - 512)];
        }
        bf16 hi = (bf16)v;
        WgiHi[idx] = hi;
        WgiLo[idx] = (bf16)(v - (float)hi);
    }
    if (idx < 384 * 128) {
        float v = W_hh[idx];
        bf16 hi = (bf16)v;
        WghHi[idx] = hi;
        WghLo[idx] = (bf16)(v - (float)hi);
    }
    if (idx < 384) {
        float sf = 0.f, sr = 0.f;
        for (int m = 0; m < 256; ++m) {
            float w = W_ih[idx * 384 + m];
            sf = fmaf(w, b2[m], sf);
            sr = fmaf(w, rb2[m], sr);
        }
        cf[idx] = sf;
        cr[idx] = sr;
    }
}

// ---------------- counting sort ----------------
__global__ void k_hist(const int* __restrict__ from_idx, const int* __restrict__ to_idx,
                       int* __restrict__ hist_to, int* __restrict__ hist_from, int E)
{
    int e = blockIdx.x * 256 + threadIdx.x;
    if (e < E) {
        atomicAdd(&hist_to[to_idx[e]], 1);
        atomicAdd(&hist_from[from_idx[e]], 1);
    }
}

// parallel scan, 3 phases. y: 0 -> A(to), 1 -> B(from)
__global__ void k_scanP(const int* __restrict__ histA, const int* __restrict__ histB,
                        int* __restrict__ ofsA, int* __restrict__ ofsB,
                        int* __restrict__ sumsA, int* __restrict__ sumsB, int n)
{
    const int* hist = blockIdx.y ? histB : histA;
    int* ofs        = blockIdx.y ? ofsB  : ofsA;
    int* sums       = blockIdx.y ? sumsB : sumsA;
    __shared__ int buf[1024];
    int i = blockIdx.x * 1024 + threadIdx.x;
    int v = (i < n) ? hist[i] : 0;
    buf[threadIdx.x] = v;
    __syncthreads();
    for (int off = 1; off < 1024; off <<= 1) {
        int t = (threadIdx.x >= off) ? buf[threadIdx.x - off] : 0;
        __syncthreads();
        buf[threadIdx.x] += t;
        __syncthreads();
    }
    if (i < n) ofs[i] = buf[threadIdx.x] - v;         // tile-local exclusive
    if (threadIdx.x == 1023) sums[blockIdx.x] = buf[1023];
}

__global__ void k_scanS(int* __restrict__ sumsA, int* __restrict__ sumsB, int nb)
{
    int* sums = blockIdx.x ? sumsB : sumsA;
    int lane = threadIdx.x;                            // 64 threads, nb <= 64
    int v = (lane < nb) ? sums[lane] : 0;
    int orig = v;
    for (int off = 1; off < 64; off <<= 1) {
        int t = __shfl_up(v, off, 64);
        if (lane >= off) v += t;
    }
    if (lane < nb) sums[lane] = v - orig;              // exclusive
}

__global__ void k_scanF(const int* __restrict__ sumsA, const int* __restrict__ sumsB,
                        int* __restrict__ ofsA, int* __restrict__ ofsB, int n)
{
    const int* sums = blockIdx.y ? sumsB : sumsA;
    int* ofs        = blockIdx.y ? ofsB  : ofsA;
    int i = blockIdx.x * 1024 + threadIdx.x;
    if (i < n) ofs[i] += sums[blockIdx.x];
}

// scatter src lists sorted by destination; post-call cur_* hold segment END offsets
__global__ void k_scatter(const int* __restrict__ from_idx, const int* __restrict__ to_idx,
                          int* __restrict__ cur_to, int* __restrict__ cur_from,
                          int* __restrict__ srcs_fwd, int* __restrict__ srcs_rev, int E)
{
    int e = blockIdx.x * 256 + threadIdx.x;
    if (e < E) {
        int f = from_idx[e], t = to_idx[e];
        int p = atomicAdd(&cur_to[t], 1);
        srcs_fwd[p] = f;                  // edges grouped by dst=t
        int q = atomicAdd(&cur_from[f], 1);
        srcs_rev[q] = t;                  // edges grouped by dst=f (reverse dir)
    }
}

// ---------------- node-level layer-1 GEMM (hi/lo split) ----------------
// One direction per launch (W1hi/W1lo pre-offset). blockIdx.y: 0 -> Pa (bf16, 1-pass),
// 1 -> Pb (f32, 3-pass exact: correlated-error path).
__global__ __launch_bounds__(256, 2) void k_nodeL1(
    const float* __restrict__ h, const bf16* __restrict__ W1hi, const bf16* __restrict__ W1lo,
    bf16* __restrict__ Pa, float* __restrict__ Pb, int N)
{
    __shared__ __align__(16) bf16 Ahh[128][136];
    __shared__ __align__(16) bf16 Ahl[128][136];
    const int tid = threadIdx.x;
    const int wave = tid >> 6, lane = tid & 63;
    const int l15 = lane & 15, lg = lane >> 4;
    const int rb = blockIdx.x * 128;
    const int table = blockIdx.y;                 // 0: a-table, 1: b-table

    #pragma unroll
    for (int it = 0; it < 16; ++it) {
        int idx = it * 256 + tid;
        int row = idx >> 5, col = (idx & 31) * 4;
        int grow = rb + row;
        float4 v = make_float4(0.f, 0.f, 0.f, 0.f);
        if (grow < N) v = *reinterpret_cast<const float4*>(&h[(size_t)grow * D_ + col]);
        bf16x4 bh, bl;
        bh[0] = (bf16)v.x; bl[0] = (bf16)(v.x - (float)bh[0]);
        bh[1] = (bf16)v.y; bl[1] = (bf16)(v.y - (float)bh[1]);
        bh[2] = (bf16)v.z; bl[2] = (bf16)(v.z - (float)bh[2]);
        bh[3] = (bf16)v.w; bl[3] = (bf16)(v.w - (float)bh[3]);
        *reinterpret_cast<bf16x4*>(&Ahh[row][col]) = bh;
        *reinterpret_cast<bf16x4*>(&Ahl[row][col]) = bl;
    }
    __syncthreads();

    f32x4 acc[8][4];
    #pragma unroll
    for (int rt = 0; rt < 8; ++rt)
        #pragma unroll
        for (int ct = 0; ct < 4; ++ct) acc[rt][ct] = f32x4{0.f, 0.f, 0.f, 0.f};

    #pragma unroll
    for (int kk = 0; kk < 4; ++kk) {
        int k0 = kk * 32 + lg * 8;
        bf16x8 ahi[8], alo[8];
        #pragma unroll
        for (int rt = 0; rt < 8; ++rt) {
            ahi[rt] = *reinterpret_cast<const bf16x8*>(&Ahh[rt * 16 + l15][k0]);
            alo[rt] = *reinterpret_cast<const bf16x8*>(&Ahl[rt * 16 + l15][k0]);
        }
        #pragma unroll
        for (int ct = 0; ct < 4; ++ct) {
            int c512 = table * 256 + wave * 64 + ct * 16 + l15;
            bf16x8 whi = *reinterpret_cast<const bf16x8*>(&W1hi[(size_t)c512 * 128 + k0]);
            #pragma unroll
            for (int rt = 0; rt < 8; ++rt)
                acc[rt][ct] = __builtin_amdgcn_mfma_f32_16x16x32_bf16(ahi[rt], whi, acc[rt][ct], 0, 0, 0);
            if (table) {   // exact path only for the correlated b-table
                bf16x8 wlo = *reinterpret_cast<const bf16x8*>(&W1lo[(size_t)c512 * 128 + k0]);
                #pragma unroll
                for (int rt = 0; rt < 8; ++rt) {
                    acc[rt][ct] = __builtin_amdgcn_mfma_f32_16x16x32_bf16(ahi[rt], wlo, acc[rt][ct], 0, 0, 0);
                    acc[rt][ct] = __builtin_amdgcn_mfma_f32_16x16x32_bf16(alo[rt], whi, acc[rt][ct], 0, 0, 0);
                }
            }
        }
    }

    if (table) {
        #pragma unroll
        for (int ct = 0; ct < 4; ++ct) {
            int col = wave * 64 + ct * 16 + l15;
            #pragma unroll
            for (int rt = 0; rt < 8; ++rt)
                #pragma unroll
                for (int r = 0; r < 4; ++r) {
                    int node = rb + rt * 16 + lg * 4 + r;   // C/D: col=l15, row=lg*4+reg
                    if (node < N) Pb[(size_t)node * TWOD_ + col] = acc[rt][ct][r];
                }
        }
    } else {
        #pragma unroll
        for (int ct = 0; ct < 4; ++ct) {
            int col = wave * 64 + ct * 16 + l15;
            #pragma unroll
            for (int rt = 0; rt < 8; ++rt)
                #pragma unroll
                for (int r = 0; r < 4; ++r) {
                    int node = rb + rt * 16 + lg * 4 + r;
                    if (node < N) Pa[(size_t)node * TWOD_ + col] = (bf16)acc[rt][ct][r];
                }
        }
    }
}

// ---------------- edge pass (atomic-free): wave v accumulates its whole segment ----------------
// S[v] = sum over segment [end[v-1], end[v]) of relu(Pa[src] + Pb[v] + b1); plain store.
__global__ __launch_bounds__(256, 8) void k_edgeS(
    const int* __restrict__ srcs, const int* __restrict__ seg_end,
    const bf16* __restrict__ Pa, const float* __restrict__ Pb,
    const float* __restrict__ b1v, float* __restrict__ S, int N)
{
    const int v = (blockIdx.x * 256 + threadIdx.x) >> 6;
    if (v >= N) return;
    const int lane = threadIdx.x & 63;
    const int c4 = lane * 4;
    const int start = (v == 0) ? 0 : seg_end[v - 1];
    const int end   = seg_end[v];

    float4 pb   = *reinterpret_cast<const float4*>(&Pb[(size_t)v * TWOD_ + c4]);
    float4 bias = *reinterpret_cast<const float4*>(&b1v[c4]);
    const float p0 = pb.x + bias.x, p1 = pb.y + bias.y;
    const float p2 = pb.z + bias.z, p3 = pb.w + bias.w;
    float a0 = 0.f, a1 = 0.f, a2 = 0.f, a3 = 0.f;

    int r = start;
    for (; r + 4 <= end; r += 4) {                  // 4 independent gathers in flight
        int s0 = srcs[r], s1 = srcs[r + 1], s2 = srcs[r + 2], s3 = srcs[r + 3];
        bf16x4 q0 = *reinterpret_cast<const bf16x4*>(&Pa[(size_t)s0 * TWOD_ + c4]);
        bf16x4 q1 = *reinterpret_cast<const bf16x4*>(&Pa[(size_t)s1 * TWOD_ + c4]);
        bf16x4 q2 = *reinterpret_cast<const bf16x4*>(&Pa[(size_t)s2 * TWOD_ + c4]);
        bf16x4 q3 = *reinterpret_cast<const bf16x4*>(&Pa[(size_t)s3 * TWOD_ + c4]);
        a0 += fmaxf((float)q0[0] + p0, 0.f); a1 += fmaxf((float)q0[1] + p1, 0.f);
        a2 += fmaxf((float)q0[2] + p2, 0.f); a3 += fmaxf((float)q0[3] + p3, 0.f);
        a0 += fmaxf((float)q1[0] + p0, 0.f); a1 += fmaxf((float)q1[1] + p1, 0.f);
        a2 += fmaxf((float)q1[2] + p2, 0.f); a3 += fmaxf((float)q1[3] + p3, 0.f);
        a0 += fmaxf((float)q2[0] + p0, 0.f); a1 += fmaxf((float)q2[1] + p1, 0.f);
        a2 += fmaxf((float)q2[2] + p2, 0.f); a3 += fmaxf((float)q2[3] + p3, 0.f);
        a0 += fmaxf((float)q3[0] + p0, 0.f); a1 += fmaxf((float)q3[1] + p1, 0.f);
        a2 += fmaxf((float)q3[2] + p2, 0.f); a3 += fmaxf((float)q3[3] + p3, 0.f);
    }
    for (; r < end; ++r) {
        int s0 = srcs[r];
        bf16x4 q0 = *reinterpret_cast<const bf16x4*>(&Pa[(size_t)s0 * TWOD_ + c4]);
        a0 += fmaxf((float)q0[0] + p0, 0.f); a1 += fmaxf((float)q0[1] + p1, 0.f);
        a2 += fmaxf((float)q0[2] + p2, 0.f); a3 += fmaxf((float)q0[3] + p3, 0.f);
    }
    *reinterpret_cast<float4*>(&S[(size_t)v * TWOD_ + c4]) = make_float4(a0, a1, a2, a3);
}

// ---------------- fused GRU-input GEMM (bf16x3 MFMA) ----------------
// gi: out[N][384] = [Sf|Sr|feat] (K=640) @ Wgi^T    (10 K-chunks)
// gh: out[N][384] = h (K=128) @ Wgh^T               (2 K-chunks)
__global__ __launch_bounds__(384, 2) void k_gemm384(
    const float* __restrict__ Sf, const float* __restrict__ Sr,
    const float* __restrict__ feat, const float* __restrict__ h,
    const bf16* __restrict__ WHi, const bf16* __restrict__ WLo,
    float* __restrict__ Og, int nch, int wK, int N)
{
    __shared__ __align__(16) bf16 Ah[128][72];
    __shared__ __align__(16) bf16 Al[128][72];
    const int tid = threadIdx.x;
    const int wave = tid >> 6, lane = tid & 63;
    const int l15 = lane & 15, lg = lane >> 4;
    const int rb = blockIdx.x * 128;
    const bool is_gh = (wK == 128);

    f32x4 acc[8][4];
    #pragma unroll
    for (int rt = 0; rt < 8; ++rt)
        #pragma unroll
        for (int ct = 0; ct < 4; ++ct) acc[rt][ct] = f32x4{0.f, 0.f, 0.f, 0.f};

    for (int ch = 0; ch < nch; ++ch) {
        const float* X; int xstride, xoff;
        if (is_gh)       { X = h;    xstride = 128; xoff = ch * 64; }
        else if (ch < 4) { X = Sf;   xstride = 256; xoff = ch * 64; }
        else if (ch < 8) { X = Sr;   xstride = 256; xoff = (ch - 4) * 64; }
        else             { X = feat; xstride = 128; xoff = (ch - 8) * 64; }
        __syncthreads();
        for (int it = tid; it < 2048; it += 384) {      // 128 rows x 16 float4
            int row = it >> 4, col = (it & 15) * 4;
            int grow = rb + row;
            float4 v = make_float4(0.f, 0.f, 0.f, 0.f);
            if (grow < N) v = *reinterpret_cast<const float4*>(&X[(size_t)grow * xstride + xoff + col]);
            bf16x4 bh, bl;
            bh[0] = (bf16)v.x; bl[0] = (bf16)(v.x - (float)bh[0]);
            bh[1] = (bf16)v.y; bl[1] = (bf16)(v.y - (float)bh[1]);
            bh[2] = (bf16)v.z; bl[2] = (bf16)(v.z - (float)bh[2]);
            bh[3] = (bf16)v.w; bl[3] = (bf16)(v.w - (float)bh[3]);
            *reinterpret_cast<bf16x4*>(&Ah[row][col]) = bh;
            *reinterpret_cast<bf16x4*>(&Al[row][col]) = bl;
        }
        __syncthreads();

        #pragma unroll
        for (int ks = 0; ks < 2; ++ks) {
            int k0 = ks * 32 + lg * 8;
            int kglob = ch * 64 + k0;
            bf16x8 ahi[8], alo[8];
            #pragma unroll
            for (int rt = 0; rt < 8; ++rt) {
                ahi[rt] = *reinterpret_cast<const bf16x8*>(&Ah[rt * 16 + l15][k0]);
                alo[rt] = *reinterpret_cast<const bf16x8*>(&Al[rt * 16 + l15][k0]);
            }
            #pragma unroll
            for (int ct = 0; ct < 4; ++ct) {
                int c = wave * 64 + ct * 16 + l15;        // 6 waves x 64 = 384 cols
                bf16x8 whi = *reinterpret_cast<const bf16x8*>(&WHi[(size_t)c * wK + kglob]);
                bf16x8 wlo = *reinterpret_cast<const bf16x8*>(&WLo[(size_t)c * wK + kglob]);
                #pragma unroll
                for (int rt = 0; rt < 8; ++rt) {
                    acc[rt][ct] = __builtin_amdgcn_mfma_f32_16x16x32_bf16(ahi[rt], whi, acc[rt][ct], 0, 0, 0);
                    acc[rt][ct] = __builtin_amdgcn_mfma_f32_16x16x32_bf16(ahi[rt], wlo, acc[rt][ct], 0, 0, 0);
                    acc[rt][ct] = __builtin_amdgcn_mfma_f32_16x16x32_bf16(alo[rt], whi, acc[rt][ct], 0, 0, 0);
                }
            }
        }
    }

    #pragma unroll
    for (int ct = 0; ct < 4; ++ct) {
        int col = wave * 64 + ct * 16 + l15;
        #pragma unroll
        for (int rt = 0; rt < 8; ++rt)
            #pragma unroll
            for (int r = 0; r < 4; ++r) {
                int node = rb + rt * 16 + lg * 4 + r;     // C/D: col=l15, row=lg*4+reg
                if (node < N) Og[(size_t)node * 384 + col] = acc[rt][ct][r];
            }
    }
}

// ---------------- gate kernel: elementwise GRU gates ----------------
__global__ void k_gate(const float* __restrict__ giG, const float* __restrict__ ghG,
                       const float* __restrict__ h,
                       const float* __restrict__ b_ih, const float* __restrict__ b_hh,
                       const float* __restrict__ cf, const float* __restrict__ cr,
                       const int* __restrict__ deg_to, const int* __restrict__ deg_from,
                       float* __restrict__ out, int N)
{
    int idx = blockIdx.x * 256 + threadIdx.x;
    if (idx >= N * D_) return;
    int node = idx >> 7, j = idx & 127;
    float dt = (float)deg_to[node], df = (float)deg_from[node];
    size_t base = (size_t)node * 384;
    float gir = giG[base + j]       + b_ih[j]       + dt * cf[j]       + df * cr[j];
    float giz = giG[base + 128 + j] + b_ih[128 + j] + dt * cf[128 + j] + df * cr[128 + j];
    float gin = giG[base + 256 + j] + b_ih[256 + j] + dt * cf[256 + j] + df * cr[256 + j];
    float ghr = ghG[base + j]       + b_hh[j];
    float ghz = ghG[base + 128 + j] + b_hh[128 + j];
    float ghn = ghG[base + 256 + j] + b_hh[256 + j];
    float rr = 1.f / (1.f + __expf(-(gir + ghr)));
    float zz = 1.f / (1.f + __expf(-(giz + ghz)));
    float nn = tanhf(gin + rr * ghn);
    out[idx] = (1.f - zz) * nn + zz * h[idx];
}

extern "C" void kernel_launch(void* const* d_in, const int* in_sizes, int n_in,
                              void* d_out, int out_size, void* d_ws, size_t ws_size,
                              hipStream_t stream)
{
    const float* h    = (const float*)d_in[0];
    const float* feat = (const float*)d_in[1];
    const float* W1   = (const float*)d_in[2];
    const float* b1   = (const float*)d_in[3];
    const float* W2   = (const float*)d_in[4];
    const float* b2   = (const float*)d_in[5];
    const float* rW1  = (const float*)d_in[6];
    const float* rb1  = (const float*)d_in[7];
    const float* rW2  = (const float*)d_in[8];
    const float* rb2  = (const float*)d_in[9];
    const float* W_ih = (const float*)d_in[10];
    const float* W_hh = (const float*)d_in[11];
    const float* b_ih = (const float*)d_in[12];
    const float* b_hh = (const float*)d_in[13];
    const int* from_idx = (const int*)d_in[14];
    const int* to_idx   = (const int*)d_in[15];
    const int E = in_sizes[14];
    const int N = in_sizes[0] / D_;
    float* out = (float*)d_out;

    // ---- workspace (~189 MB peak; known-good scale) ----
    char* p = (char*)d_ws;
    auto take = [&](size_t bytes) { char* r = p; p += (bytes + 255) & ~(size_t)255; return r; };
    // P block (76.8 MB): Pa bf16 [N,256] + Pb f32 [N,256] during edge phase;
    // reused as giG f32 [N,384] afterwards (sizes match exactly).
    char*  Pblk      = take((size_t)N * TWOD_ * (sizeof(bf16) + sizeof(float)));
    bf16*  Pa        = (bf16*)Pblk;
    float* Pb        = (float*)(Pblk + (size_t)N * TWOD_ * sizeof(bf16));
    float* giG       = (float*)Pblk;
    // S block (102.4 MB): S_fwd + S_rev f32 [N,256]; reused as ghG f32 [N,384] (76.8 MB)
    char*  Sblk      = take((size_t)2 * N * TWOD_ * sizeof(float));
    float* S_fwd     = (float*)Sblk;
    float* S_rev     = (float*)(Sblk + (size_t)N * TWOD_ * sizeof(float));
    float* ghG       = (float*)Sblk;
    int*   srcs_fwd  = (int*)  take((size_t)E * sizeof(int));
    int*   srcs_rev  = (int*)  take((size_t)E * sizeof(int));
    bf16*  W1chi     = (bf16*) take(1024 * 128 * sizeof(bf16));
    bf16*  W1clo     = (bf16*) take(1024 * 128 * sizeof(bf16));
    bf16*  WgiHi     = (bf16*) take(384 * 640 * sizeof(bf16));
    bf16*  WgiLo     = (bf16*) take(384 * 640 * sizeof(bf16));
    bf16*  WghHi     = (bf16*) take(384 * 128 * sizeof(bf16));
    bf16*  WghLo     = (bf16*) take(384 * 128 * sizeof(bf16));
    float* cf        = (float*)take(384 * sizeof(float));
    float* cr        = (float*)take(384 * sizeof(float));
    int*   hist_to   = (int*)  take((size_t)N * sizeof(int));
    int*   hist_from = (int*)  take((size_t)N * sizeof(int));
    int*   ofs_to    = (int*)  take((size_t)N * sizeof(int));
    int*   ofs_from  = (int*)  take((size_t)N * sizeof(int));
    int*   sumsA     = (int*)  take(64 * sizeof(int));
    int*   sumsB     = (int*)  take(64 * sizeof(int));

    hipMemsetAsync(hist_to, 0, (size_t)N * sizeof(int), stream);
    hipMemsetAsync(hist_from, 0, (size_t)N * sizeof(int), stream);

    k_prep<<<512, 256, 0, stream>>>(W1, rW1, W1chi, W1clo);
    k_fold<<<960, 256, 0, stream>>>(W_ih, W_hh, W2, rW2, b2, rb2,
                                    WgiHi, WgiLo, WghHi, WghLo, cf, cr);

    int gE = (E + 255) / 256;
    k_hist<<<gE, 256, 0, stream>>>(from_idx, to_idx, hist_to, hist_from, E);
    int nb = (N + 1023) / 1024;                       // 49 <= 64
    k_scanP<<<dim3(nb, 2), 1024, 0, stream>>>(hist_to, hist_from, ofs_to, ofs_from,
                                              sumsA, sumsB, N);
    k_scanS<<<2, 64, 0, stream>>>(sumsA, sumsB, nb);
    k_scanF<<<dim3(nb, 2), 1024, 0, stream>>>(sumsA, sumsB, ofs_to, ofs_from, N);
    k_scatter<<<gE, 256, 0, stream>>>(from_idx, to_idx, ofs_to, ofs_from,
                                      srcs_fwd, srcs_rev, E);
    // post-scatter: ofs_to[v] / ofs_from[v] are segment END offsets per node

    dim3 g1((N + 127) / 128, 2);
    int gEdgeS = (N + 3) / 4;                         // 4 nodes (waves) per 256-thread block

    // forward direction (W1 rows 0..511 of packed table)
    k_nodeL1<<<g1, 256, 0, stream>>>(h, W1chi, W1clo, Pa, Pb, N);
    k_edgeS<<<gEdgeS, 256, 0, stream>>>(srcs_fwd, ofs_to, Pa, Pb, b1, S_fwd, N);
    // reverse direction (rW1 rows 512..1023), reusing Pa/Pb
    k_nodeL1<<<g1, 256, 0, stream>>>(h, W1chi + 512 * 128, W1clo + 512 * 128, Pa, Pb, N);
    k_edgeS<<<gEdgeS, 256, 0, stream>>>(srcs_rev, ofs_from, Pa, Pb, rb1, S_rev, N);

    int gN = (N + 127) / 128;
    // gi: consumes Sf/Sr/feat, writes giG (over dead P block)
    k_gemm384<<<gN, 384, 0, stream>>>(S_fwd, S_rev, feat, h, WgiHi, WgiLo, giG, 10, 640, N);
    // gh: reads only h, writes ghG (over dead S block) — ordered after gi by stream
    k_gemm384<<<gN, 384, 0, stream>>>(S_fwd, S_rev, feat, h, WghHi, WghLo, ghG, 2, 128, N);

    k_gate<<<(N * D_ + 255) / 256, 256, 0, stream>>>(giG, ghG, h, b_ih, b_hh, cf, cr,
                                                     hist_to, hist_from, out, N);
}